// Round 6
// baseline (663.517 us; speedup 1.0000x reference)
//
#include <hip/hip_runtime.h>
#include <math.h>

typedef __bf16 bf16;
typedef __attribute__((ext_vector_type(4))) __bf16 bf16x4;
typedef __attribute__((ext_vector_type(8))) __bf16 bf16x8;
typedef __attribute__((ext_vector_type(4))) float f32x4;

#define D_MODEL 1024
#define NH 16
#define DP 64
#define BB 2
#define SEQ 2048
#define TOK 4096   // B*S
#define FFD 4096

// ---- async global->LDS (wave-uniform LDS base + lane*16, m97 pattern) ----
__device__ __forceinline__ void async16(bf16* lds, const bf16* g) {
    __builtin_amdgcn_global_load_lds(
        (__attribute__((address_space(1))) void*)g,
        (__attribute__((address_space(3))) void*)lds, 16, 0, 0);
}

__device__ __forceinline__ f32x4 mfma16(bf16x8 a, bf16x8 b, f32x4 c) {
    return __builtin_amdgcn_mfma_f32_16x16x32_bf16(a, b, c, 0, 0, 0);
}

// ======================= LayerNorm (unbiased std, eps on std) ==============
template<typename TIN>
__global__ __launch_bounds__(256) void ln_kernel(
    const TIN* __restrict__ in, const float* __restrict__ g,
    const float* __restrict__ be, bf16* __restrict__ out)
{
    const size_t row = blockIdx.x;
    const int t = threadIdx.x;
    const TIN* x = in + row * D_MODEL;

    float v0, v1, v2, v3;
    if constexpr (sizeof(TIN) == 4) {
        const float4 xv = *(const float4*)(x + t * 4);
        v0 = xv.x; v1 = xv.y; v2 = xv.z; v3 = xv.w;
    } else {
        const bf16x4 xv = *(const bf16x4*)(x + t * 4);
        v0 = (float)xv[0]; v1 = (float)xv[1]; v2 = (float)xv[2]; v3 = (float)xv[3];
    }
    float s  = v0 + v1 + v2 + v3;
    float ss = v0*v0 + v1*v1 + v2*v2 + v3*v3;
    #pragma unroll
    for (int off = 32; off > 0; off >>= 1) {
        s  += __shfl_down(s, off);
        ss += __shfl_down(ss, off);
    }
    __shared__ float rs[4], rss[4];
    if ((t & 63) == 0) { rs[t >> 6] = s; rss[t >> 6] = ss; }
    __syncthreads();
    const float S  = rs[0] + rs[1] + rs[2] + rs[3];
    const float SS = rss[0] + rss[1] + rss[2] + rss[3];
    const float mean = S * (1.0f / 1024.0f);
    const float var  = fmaxf((SS - S * mean) * (1.0f / 1023.0f), 0.0f);
    const float inv  = 1.0f / (sqrtf(var) + 1e-6f);

    const float4 gv = *(const float4*)(g  + t * 4);
    const float4 bv = *(const float4*)(be + t * 4);
    bf16x4 ov;
    ov[0] = (bf16)(gv.x * ((v0 - mean) * inv) + bv.x);
    ov[1] = (bf16)(gv.y * ((v1 - mean) * inv) + bv.y);
    ov[2] = (bf16)(gv.z * ((v2 - mean) * inv) + bv.z);
    ov[3] = (bf16)(gv.w * ((v3 - mean) * inv) + bv.w);
    *(bf16x4*)(out + row * D_MODEL + t * 4) = ov;
}

// ============ NT GEMM: C[m,n] = sum_k A[m,k]*W[n,k], A bf16, W fp32 ========
// EPI 0: qkv scatter (v+bias)*scale -> [B,H,S,DP] (TOUT=bf16)
// EPI 1: +bias +res -> C (dense -> h; res may alias C elementwise)
// EPI 2: exact gelu -> C (fc -> ff1)
// EPI 3: +res -> C (proj -> out, TOUT=float for fp32 d_out)
template<int EPI, typename TOUT>
__global__ __launch_bounds__(256, 2) void gemm_bt(
    const bf16* __restrict__ A, const float* __restrict__ W,
    const float* __restrict__ bias, const bf16* res,
    TOUT* C, int M, int N, int K, float scale)
{
    __shared__ __align__(16) bf16 As[128 * 32];
    __shared__ __align__(16) bf16 Bs[128 * 32];
    const int t = threadIdx.x;
    const int w = t >> 6, lane = t & 63;
    const int fr = lane & 15, quad = lane >> 4;
    const int m0 = blockIdx.y * 128, n0 = blockIdx.x * 128;
    const int wm = (w >> 1) * 64, wn = (w & 1) * 64;

    const f32x4 z = {0.f, 0.f, 0.f, 0.f};
    f32x4 acc[4][4];
    #pragma unroll
    for (int i = 0; i < 4; ++i)
        #pragma unroll
        for (int j = 0; j < 4; ++j) acc[i][j] = z;

    const int nk = K >> 5;
    for (int kt = 0; kt < nk; ++kt) {
        const int k0 = kt << 5;
        #pragma unroll
        for (int call = 0; call < 2; ++call) {
            const int c = call * 256 + t;
            const int row = c >> 2, sub = c & 3;
            async16(&As[(size_t)(call * 256 + w * 64) * 8],
                    A + (size_t)(m0 + row) * K + k0 + sub * 8);
        }
        #pragma unroll
        for (int i = 0; i < 4; ++i) {
            const int f = i * 256 + t;           // float4 idx in [0,1024)
            const int row = f >> 3, k4 = f & 7;
            const float4 wv = *(const float4*)(W + (size_t)(n0 + row) * K + k0 + k4 * 4);
            bf16x4 o; o[0] = (bf16)wv.x; o[1] = (bf16)wv.y;
            o[2] = (bf16)wv.z; o[3] = (bf16)wv.w;
            *(bf16x4*)&Bs[row * 32 + k4 * 4] = o;
        }
        __syncthreads();
        bf16x8 af[4], bfr[4];
        #pragma unroll
        for (int i = 0; i < 4; ++i)
            af[i] = *(const bf16x8*)&As[(wm + i * 16 + fr) * 32 + quad * 8];
        #pragma unroll
        for (int j = 0; j < 4; ++j)
            bfr[j] = *(const bf16x8*)&Bs[(wn + j * 16 + fr) * 32 + quad * 8];
        #pragma unroll
        for (int i = 0; i < 4; ++i)
            #pragma unroll
            for (int j = 0; j < 4; ++j)
                acc[i][j] = mfma16(af[i], bfr[j], acc[i][j]);
        __syncthreads();
    }

    // Epilogue. C/D layout (m89): col = lane&15, row = quad*4 + reg.
    #pragma unroll
    for (int i = 0; i < 4; ++i) {
        #pragma unroll
        for (int j = 0; j < 4; ++j) {
            #pragma unroll
            for (int r = 0; r < 4; ++r) {
                const int m = m0 + wm + i * 16 + quad * 4 + r;
                const int n = n0 + wn + j * 16 + fr;
                float v = acc[i][j][r];
                if (EPI == 0) {
                    v = (v + bias[n]) * scale;
                    const int b = m >> 11, s = m & 2047, h = n >> 6, d = n & 63;
                    C[(((size_t)(b * NH + h)) * SEQ + s) * DP + d] = (TOUT)v;
                } else if (EPI == 1) {
                    v += bias[n];
                    v += (float)res[(size_t)m * N + n];
                    C[(size_t)m * N + n] = (TOUT)v;
                } else if (EPI == 2) {
                    v = 0.5f * v * (1.0f + erff(v * 0.70710678118f));
                    C[(size_t)m * N + n] = (TOUT)v;
                } else {
                    v += (float)res[(size_t)m * N + n];
                    C[(size_t)m * N + n] = (TOUT)v;
                }
            }
        }
    }
}

// ======================= Flash attention (causal) ==========================
// q,k,v: [B*H, S, DP] bf16, q pre-scaled by 1/8. ctx: [B, S, D_MODEL].
__global__ __launch_bounds__(256, 2) void attn_kernel(
    const bf16* __restrict__ q, const bf16* __restrict__ k,
    const bf16* __restrict__ v, bf16* __restrict__ ctx)
{
    __shared__ __align__(16) bf16 Ks[64 * 64];
    __shared__ __align__(16) bf16 Vs[64 * 64];
    __shared__ __align__(16) bf16 Ps[4][16 * 64];
    const int t = threadIdx.x, wv = t >> 6, lane = t & 63;
    const int fr = lane & 15, quad = lane >> 4;
    const int bh = blockIdx.y;
    const int q0 = blockIdx.x * 64;
    const size_t base = (size_t)bh * SEQ * DP;
    const int qr0 = q0 + wv * 16;

    bf16x8 qf[2];
    #pragma unroll
    for (int c = 0; c < 2; ++c)
        qf[c] = *(const bf16x8*)(q + base + (size_t)(qr0 + fr) * DP + c * 32 + quad * 8);

    const f32x4 z = {0.f, 0.f, 0.f, 0.f};
    f32x4 o[4] = {z, z, z, z};
    float mi[4] = {-1e30f, -1e30f, -1e30f, -1e30f};
    float li[4] = {0.f, 0.f, 0.f, 0.f};

    const int nkt = blockIdx.x + 1;
    for (int kt = 0; kt < nkt; ++kt) {
        const int kk0 = kt * 64;
        __syncthreads();  // all waves done reading Ks/Vs of previous iter
        #pragma unroll
        for (int call = 0; call < 2; ++call) {
            const int c = call * 256 + t;
            const int row = c >> 3, sub = c & 7;
            async16(&Ks[(size_t)(call * 256 + wv * 64) * 8],
                    k + base + (size_t)(kk0 + row) * DP + sub * 8);
            async16(&Vs[(size_t)(call * 256 + wv * 64) * 8],
                    v + base + (size_t)(kk0 + row) * DP + sub * 8);
        }
        __syncthreads();

        // S = q k^T  (q pre-scaled)
        f32x4 sa[4] = {z, z, z, z};
        #pragma unroll
        for (int nb = 0; nb < 4; ++nb)
            #pragma unroll
            for (int c = 0; c < 2; ++c) {
                bf16x8 kf = *(const bf16x8*)&Ks[(nb * 16 + fr) * 64 + c * 32 + quad * 8];
                sa[nb] = mfma16(qf[c], kf, sa[nb]);
            }

        float p[4][4], rmax[4];
        #pragma unroll
        for (int r = 0; r < 4; ++r) rmax[r] = -1e30f;
        #pragma unroll
        for (int nb = 0; nb < 4; ++nb)
            #pragma unroll
            for (int r = 0; r < 4; ++r) {
                const int key = kk0 + nb * 16 + fr;
                const int qrow = qr0 + quad * 4 + r;
                float sv = sa[nb][r];
                if (key > qrow) sv += -1e9f;
                p[nb][r] = sv;
                rmax[r] = fmaxf(rmax[r], sv);
            }
        #pragma unroll
        for (int off = 1; off < 16; off <<= 1)
            #pragma unroll
            for (int r = 0; r < 4; ++r)
                rmax[r] = fmaxf(rmax[r], __shfl_xor(rmax[r], off));

        float alpha[4], psum[4];
        #pragma unroll
        for (int r = 0; r < 4; ++r) {
            const float nm = fmaxf(mi[r], rmax[r]);
            alpha[r] = __expf(mi[r] - nm);
            mi[r] = nm;
            float ps = 0.f;
            #pragma unroll
            for (int nb = 0; nb < 4; ++nb) {
                const float e = __expf(p[nb][r] - nm);
                p[nb][r] = e;
                ps += e;
            }
            psum[r] = ps;
        }
        #pragma unroll
        for (int off = 1; off < 16; off <<= 1)
            #pragma unroll
            for (int r = 0; r < 4; ++r)
                psum[r] += __shfl_xor(psum[r], off);
        #pragma unroll
        for (int r = 0; r < 4; ++r) li[r] = li[r] * alpha[r] + psum[r];
        #pragma unroll
        for (int db = 0; db < 4; ++db)
            #pragma unroll
            for (int r = 0; r < 4; ++r) o[db][r] *= alpha[r];

        // P: C-layout -> LDS row-major [16][64]
        #pragma unroll
        for (int nb = 0; nb < 4; ++nb)
            #pragma unroll
            for (int r = 0; r < 4; ++r)
                Ps[wv][(quad * 4 + r) * 64 + nb * 16 + fr] = (bf16)p[nb][r];
        __syncthreads();

        // PV: A = P (A-layout: m=lane&15, k=quad*8+j), B = V[key][d]
        bf16x8 pf[2];
        #pragma unroll
        for (int c = 0; c < 2; ++c)
            pf[c] = *(const bf16x8*)&Ps[wv][fr * 64 + c * 32 + quad * 8];
        #pragma unroll
        for (int db = 0; db < 4; ++db)
            #pragma unroll
            for (int c = 0; c < 2; ++c) {
                bf16x8 vf;
                #pragma unroll
                for (int j = 0; j < 8; ++j)
                    vf[j] = Vs[(c * 32 + quad * 8 + j) * 64 + db * 16 + fr];
                o[db] = mfma16(pf[c], vf, o[db]);
            }
    }

    const int b = bh >> 4, hh = bh & 15;
    #pragma unroll
    for (int db = 0; db < 4; ++db)
        #pragma unroll
        for (int r = 0; r < 4; ++r) {
            const int qrow = qr0 + quad * 4 + r;
            const int d = db * 16 + fr;
            ctx[((size_t)(b * SEQ + qrow)) * D_MODEL + hh * DP + d] =
                (bf16)(o[db][r] / li[r]);
        }
}

// ======================= launcher ==========================================
// fp32 inputs, fp32 output (R5 evidence: bit-identical error across attn
// impls => d_out decoded as fp32). Internal activations bf16. Arena 40 MiB:
//   [0,4M):  xn -> h -> hn (in place)
//   [4,8M):  qb   [8,12M): kb   [12,16M): vb   [16,20M): ctx
//   ff1 = [4,20M) overlay (qb/kb/vb dead after attn, ctx dead after dense)
extern "C" void kernel_launch(void* const* d_in, const int* in_sizes, int n_in,
                              void* d_out, int out_size, void* d_ws, size_t ws_size,
                              hipStream_t stream) {
    const float* x       = (const float*)d_in[0];
    const float* wq_w    = (const float*)d_in[2];
    const float* wq_b    = (const float*)d_in[3];
    const float* wk_w    = (const float*)d_in[4];
    const float* wk_b    = (const float*)d_in[5];
    const float* wv_w    = (const float*)d_in[6];
    const float* wv_b    = (const float*)d_in[7];
    const float* dense_w = (const float*)d_in[8];
    const float* dense_b = (const float*)d_in[9];
    const float* gamma1  = (const float*)d_in[10];
    const float* beta1   = (const float*)d_in[11];
    const float* gamma2  = (const float*)d_in[12];
    const float* beta2   = (const float*)d_in[13];
    const float* fc_w    = (const float*)d_in[14];
    const float* proj_w  = (const float*)d_in[15];
    float* out = (float*)d_out;

    bf16* ws = (bf16*)d_ws;
    const size_t M4 = (size_t)4 << 20;
    bf16* xn  = ws;             // -> h -> hn in place
    bf16* qb  = ws + M4;
    bf16* kb  = ws + 2 * M4;
    bf16* vb  = ws + 3 * M4;
    bf16* ctx = ws + 4 * M4;
    bf16* ff1 = qb;             // 16M elems overlay
    bf16* h = xn, *hn = xn;

    ln_kernel<float><<<TOK, 256, 0, stream>>>(x, gamma1, beta1, xn);
    gemm_bt<0, bf16><<<dim3(8, 32), 256, 0, stream>>>(xn, wq_w, wq_b, nullptr, qb,
                                                      TOK, D_MODEL, D_MODEL, 0.125f);
    gemm_bt<0, bf16><<<dim3(8, 32), 256, 0, stream>>>(xn, wk_w, wk_b, nullptr, kb,
                                                      TOK, D_MODEL, D_MODEL, 1.0f);
    gemm_bt<0, bf16><<<dim3(8, 32), 256, 0, stream>>>(xn, wv_w, wv_b, nullptr, vb,
                                                      TOK, D_MODEL, D_MODEL, 1.0f);
    attn_kernel<<<dim3(SEQ / 64, BB * NH), 256, 0, stream>>>(qb, kb, vb, ctx);
    gemm_bt<1, bf16><<<dim3(8, 32), 256, 0, stream>>>(ctx, dense_w, dense_b, xn, h,
                                                      TOK, D_MODEL, D_MODEL, 1.0f);
    ln_kernel<bf16><<<TOK, 256, 0, stream>>>(h, gamma2, beta2, hn);
    gemm_bt<2, bf16><<<dim3(32, 32), 256, 0, stream>>>(hn, fc_w, nullptr, nullptr, ff1,
                                                       TOK, FFD, D_MODEL, 1.0f);
    gemm_bt<3, float><<<dim3(8, 32), 256, 0, stream>>>(ff1, proj_w, nullptr, hn, out,
                                                       TOK, D_MODEL, FFD, 1.0f);
}

// Round 8
// 478.127 us; speedup vs baseline: 1.3877x; 1.3877x over previous
//
#include <hip/hip_runtime.h>
#include <math.h>

typedef __bf16 bf16;
typedef __attribute__((ext_vector_type(4))) __bf16 bf16x4;
typedef __attribute__((ext_vector_type(8))) __bf16 bf16x8;
typedef __attribute__((ext_vector_type(4))) float f32x4;

#define D_MODEL 1024
#define NH 16
#define DP 64
#define BB 2
#define SEQ 2048
#define TOK 4096   // B*S
#define FFD 4096
#define VST 72     // padded LDS row stride (elems): mult of 8 (16B align), bank-spreading

// ---- async global->LDS (wave-uniform LDS base + lane*16, m97 pattern) ----
__device__ __forceinline__ void async16(bf16* lds, const bf16* g) {
    __builtin_amdgcn_global_load_lds(
        (__attribute__((address_space(1))) void*)g,
        (__attribute__((address_space(3))) void*)lds, 16, 0, 0);
}

__device__ __forceinline__ f32x4 mfma16(bf16x8 a, bf16x8 b, f32x4 c) {
    return __builtin_amdgcn_mfma_f32_16x16x32_bf16(a, b, c, 0, 0, 0);
}

// ================= fp32 -> bf16 weight pre-conversion ======================
__global__ __launch_bounds__(256) void cvt_w(
    const float4* __restrict__ in, bf16x4* __restrict__ out, int n4)
{
    const int i = blockIdx.x * 256 + threadIdx.x;
    if (i >= n4) return;
    const float4 v = in[i];
    bf16x4 o; o[0] = (bf16)v.x; o[1] = (bf16)v.y; o[2] = (bf16)v.z; o[3] = (bf16)v.w;
    out[i] = o;
}

// ======================= LayerNorm (unbiased std, eps on std) ==============
template<typename TIN>
__global__ __launch_bounds__(256) void ln_kernel(
    const TIN* __restrict__ in, const float* __restrict__ g,
    const float* __restrict__ be, bf16* __restrict__ out)
{
    const size_t row = blockIdx.x;
    const int t = threadIdx.x;
    const TIN* x = in + row * D_MODEL;

    float v0, v1, v2, v3;
    if constexpr (sizeof(TIN) == 4) {
        const float4 xv = *(const float4*)(x + t * 4);
        v0 = xv.x; v1 = xv.y; v2 = xv.z; v3 = xv.w;
    } else {
        const bf16x4 xv = *(const bf16x4*)(x + t * 4);
        v0 = (float)xv[0]; v1 = (float)xv[1]; v2 = (float)xv[2]; v3 = (float)xv[3];
    }
    float s  = v0 + v1 + v2 + v3;
    float ss = v0*v0 + v1*v1 + v2*v2 + v3*v3;
    #pragma unroll
    for (int off = 32; off > 0; off >>= 1) {
        s  += __shfl_down(s, off);
        ss += __shfl_down(ss, off);
    }
    __shared__ float rs[4], rss[4];
    if ((t & 63) == 0) { rs[t >> 6] = s; rss[t >> 6] = ss; }
    __syncthreads();
    const float S  = rs[0] + rs[1] + rs[2] + rs[3];
    const float SS = rss[0] + rss[1] + rss[2] + rss[3];
    const float mean = S * (1.0f / 1024.0f);
    const float var  = fmaxf((SS - S * mean) * (1.0f / 1023.0f), 0.0f);
    const float inv  = 1.0f / (sqrtf(var) + 1e-6f);

    const float4 gv = *(const float4*)(g  + t * 4);
    const float4 bv = *(const float4*)(be + t * 4);
    bf16x4 ov;
    ov[0] = (bf16)(gv.x * ((v0 - mean) * inv) + bv.x);
    ov[1] = (bf16)(gv.y * ((v1 - mean) * inv) + bv.y);
    ov[2] = (bf16)(gv.z * ((v2 - mean) * inv) + bv.z);
    ov[3] = (bf16)(gv.w * ((v3 - mean) * inv) + bv.w);
    *(bf16x4*)(out + row * D_MODEL + t * 4) = ov;
}

// ============ NT GEMM: C[m,n] = sum_k A[m,k]*W[n,k], A,W bf16 ==============
// EPI 0: qkv scatter (v+bias)*scale -> [B,H,S,DP]
// EPI 1: +bias +res -> C   EPI 2: exact gelu -> C   EPI 3: +res -> C
template<int EPI, typename TOUT>
__global__ __launch_bounds__(256, 2) void gemm_bt(
    const bf16* __restrict__ A, const bf16* __restrict__ W,
    const float* __restrict__ bias, const bf16* res,
    TOUT* C, int M, int N, int K, float scale)
{
    __shared__ __align__(16) bf16 As[128 * 32];
    __shared__ __align__(16) bf16 Bs[128 * 32];
    const int t = threadIdx.x;
    const int w = t >> 6, lane = t & 63;
    const int fr = lane & 15, quad = lane >> 4;
    const int m0 = blockIdx.y * 128, n0 = blockIdx.x * 128;
    const int wm = (w >> 1) * 64, wn = (w & 1) * 64;

    const f32x4 z = {0.f, 0.f, 0.f, 0.f};
    f32x4 acc[4][4];
    #pragma unroll
    for (int i = 0; i < 4; ++i)
        #pragma unroll
        for (int j = 0; j < 4; ++j) acc[i][j] = z;

    const int nk = K >> 5;
    for (int kt = 0; kt < nk; ++kt) {
        const int k0 = kt << 5;
        #pragma unroll
        for (int call = 0; call < 2; ++call) {
            const int c = call * 256 + t;
            const int row = c >> 2, sub = c & 3;
            async16(&As[(size_t)(call * 256 + w * 64) * 8],
                    A + (size_t)(m0 + row) * K + k0 + sub * 8);
            async16(&Bs[(size_t)(call * 256 + w * 64) * 8],
                    W + (size_t)(n0 + row) * K + k0 + sub * 8);
        }
        __syncthreads();
        bf16x8 af[4], bfr[4];
        #pragma unroll
        for (int i = 0; i < 4; ++i)
            af[i] = *(const bf16x8*)&As[(wm + i * 16 + fr) * 32 + quad * 8];
        #pragma unroll
        for (int j = 0; j < 4; ++j)
            bfr[j] = *(const bf16x8*)&Bs[(wn + j * 16 + fr) * 32 + quad * 8];
        #pragma unroll
        for (int i = 0; i < 4; ++i)
            #pragma unroll
            for (int j = 0; j < 4; ++j)
                acc[i][j] = mfma16(af[i], bfr[j], acc[i][j]);
        __syncthreads();
    }

    // Epilogue. C/D layout (m89): col = lane&15, row = quad*4 + reg.
    #pragma unroll
    for (int i = 0; i < 4; ++i) {
        #pragma unroll
        for (int j = 0; j < 4; ++j) {
            #pragma unroll
            for (int r = 0; r < 4; ++r) {
                const int m = m0 + wm + i * 16 + quad * 4 + r;
                const int n = n0 + wn + j * 16 + fr;
                float v = acc[i][j][r];
                if (EPI == 0) {
                    v = (v + bias[n]) * scale;
                    const int b = m >> 11, s = m & 2047, h = n >> 6, d = n & 63;
                    C[(((size_t)(b * NH + h)) * SEQ + s) * DP + d] = (TOUT)v;
                } else if (EPI == 1) {
                    v += bias[n];
                    v += (float)res[(size_t)m * N + n];
                    C[(size_t)m * N + n] = (TOUT)v;
                } else if (EPI == 2) {
                    v = 0.5f * v * (1.0f + erff(v * 0.70710678118f));
                    C[(size_t)m * N + n] = (TOUT)v;
                } else {
                    v += (float)res[(size_t)m * N + n];
                    C[(size_t)m * N + n] = (TOUT)v;
                }
            }
        }
    }
}

// ======================= Flash attention (causal, balanced) ================
// q,k,v: [B*H, S, DP] bf16, q pre-scaled by 1/8. ctx: [B, S, D_MODEL].
// Each block handles q-tile pair (x, 31-x) sequentially: uniform 33 tile-steps.
__global__ __launch_bounds__(256, 2) void attn_kernel(
    const bf16* __restrict__ q, const bf16* __restrict__ k,
    const bf16* __restrict__ v, bf16* __restrict__ ctx)
{
    __shared__ __align__(16) bf16 Ks[2][64 * 32];   // [c-half][key][d32] stride 32
    __shared__ __align__(16) bf16 VsT[64 * VST];    // [d][key] padded
    __shared__ __align__(16) bf16 Ps[4][16 * VST];  // per-wave P, padded
    const int t = threadIdx.x, wv = t >> 6, lane = t & 63;
    const int fr = lane & 15, quad = lane >> 4;
    const int bh = blockIdx.y;
    const size_t base = (size_t)bh * SEQ * DP;
    const int b = bh >> 4, hh = bh & 15;
    const f32x4 z = {0.f, 0.f, 0.f, 0.f};

    for (int half = 0; half < 2; ++half) {
        const int qt = half ? (31 - (int)blockIdx.x) : (int)blockIdx.x;
        const int q0 = qt * 64;
        const int qr0 = q0 + wv * 16;

        bf16x8 qf[2];
        #pragma unroll
        for (int c = 0; c < 2; ++c)
            qf[c] = *(const bf16x8*)(q + base + (size_t)(qr0 + fr) * DP + c * 32 + quad * 8);

        f32x4 o[4] = {z, z, z, z};
        float mi[4] = {-1e30f, -1e30f, -1e30f, -1e30f};
        float li[4] = {0.f, 0.f, 0.f, 0.f};

        const int nkt = qt + 1;
        for (int kt = 0; kt < nkt; ++kt) {
            const int kk0 = kt * 64;
            __syncthreads();  // prev iter's Ks/VsT reads complete
            // K tile: async16 into split layout [c][key 0..63][d 0..31]
            // lane l of wave wv: row=16wv+(l>>2), chunk=l&3 -> LDS wavebase+16l
            {
                const int row = t >> 2, chunk = t & 3;
                async16(&Ks[0][(size_t)(wv * 64) * 8],
                        k + base + (size_t)(kk0 + row) * DP + 0 * 32 + chunk * 8);
                async16(&Ks[1][(size_t)(wv * 64) * 8],
                        k + base + (size_t)(kk0 + row) * DP + 1 * 32 + chunk * 8);
            }
            // V tile: register-staged TRANSPOSED into VsT[d][key]
            #pragma unroll
            for (int it = 0; it < 2; ++it) {
                const int cidx = it * 256 + t;        // [0,512)
                const int row = cidx >> 3;            // key 0..63
                const int c0 = (cidx & 7) * 8;        // d start
                const bf16x8 vv = *(const bf16x8*)(v + base + (size_t)(kk0 + row) * DP + c0);
                #pragma unroll
                for (int j = 0; j < 8; ++j)
                    VsT[(c0 + j) * VST + row] = vv[j];
            }
            __syncthreads();

            // S = q k^T
            f32x4 sa[4] = {z, z, z, z};
            #pragma unroll
            for (int nb = 0; nb < 4; ++nb)
                #pragma unroll
                for (int c = 0; c < 2; ++c) {
                    const bf16x8 kf = *(const bf16x8*)&Ks[c][(nb * 16 + fr) * 32 + quad * 8];
                    sa[nb] = mfma16(qf[c], kf, sa[nb]);
                }

            float p[4][4], rmax[4];
            #pragma unroll
            for (int r = 0; r < 4; ++r) rmax[r] = -1e30f;
            #pragma unroll
            for (int nb = 0; nb < 4; ++nb)
                #pragma unroll
                for (int r = 0; r < 4; ++r) {
                    const int key = kk0 + nb * 16 + fr;
                    const int qrow = qr0 + quad * 4 + r;
                    float sv = sa[nb][r];
                    if (key > qrow) sv += -1e9f;
                    p[nb][r] = sv;
                    rmax[r] = fmaxf(rmax[r], sv);
                }
            #pragma unroll
            for (int off = 1; off < 16; off <<= 1)
                #pragma unroll
                for (int r = 0; r < 4; ++r)
                    rmax[r] = fmaxf(rmax[r], __shfl_xor(rmax[r], off));

            float alpha[4], psum[4];
            #pragma unroll
            for (int r = 0; r < 4; ++r) {
                const float nm = fmaxf(mi[r], rmax[r]);
                alpha[r] = __expf(mi[r] - nm);
                mi[r] = nm;
                float ps = 0.f;
                #pragma unroll
                for (int nb = 0; nb < 4; ++nb) {
                    const float e = __expf(p[nb][r] - nm);
                    p[nb][r] = e;
                    ps += e;
                }
                psum[r] = ps;
            }
            #pragma unroll
            for (int off = 1; off < 16; off <<= 1)
                #pragma unroll
                for (int r = 0; r < 4; ++r)
                    psum[r] += __shfl_xor(psum[r], off);
            #pragma unroll
            for (int r = 0; r < 4; ++r) li[r] = li[r] * alpha[r] + psum[r];
            #pragma unroll
            for (int db = 0; db < 4; ++db)
                #pragma unroll
                for (int r = 0; r < 4; ++r) o[db][r] *= alpha[r];

            // P: C-layout -> wave-private LDS (same-wave DS ordering suffices)
            #pragma unroll
            for (int nb = 0; nb < 4; ++nb)
                #pragma unroll
                for (int r = 0; r < 4; ++r)
                    Ps[wv][(quad * 4 + r) * VST + nb * 16 + fr] = (bf16)p[nb][r];

            // PV: A = P (A-layout), B = V^T rows (vector b128, padded stride)
            bf16x8 pf[2];
            #pragma unroll
            for (int c = 0; c < 2; ++c)
                pf[c] = *(const bf16x8*)&Ps[wv][fr * VST + c * 32 + quad * 8];
            #pragma unroll
            for (int db = 0; db < 4; ++db)
                #pragma unroll
                for (int c = 0; c < 2; ++c) {
                    const bf16x8 vf = *(const bf16x8*)&VsT[(db * 16 + fr) * VST + c * 32 + quad * 8];
                    o[db] = mfma16(pf[c], vf, o[db]);
                }
        }

        #pragma unroll
        for (int db = 0; db < 4; ++db)
            #pragma unroll
            for (int r = 0; r < 4; ++r) {
                const int qrow = qr0 + quad * 4 + r;
                const int d = db * 16 + fr;
                ctx[((size_t)(b * SEQ + qrow)) * D_MODEL + hh * DP + d] =
                    (bf16)(o[db][r] / li[r]);
            }
    }
}

// ======================= launcher ==========================================
// fp32 inputs, fp32 output. Internal bf16. Arena (bf16 elems, 64 MiB):
//   [0,4M): xn -> h -> hn   [4,8M): qb  [8,12M): kb  [12,16M): vb  [16,20M): ctx
//   ff1 = [4,20M) overlay   [20,24M): wq/wk/wv/wd bf16   [24,28M): fc  [28,32M): proj
extern "C" void kernel_launch(void* const* d_in, const int* in_sizes, int n_in,
                              void* d_out, int out_size, void* d_ws, size_t ws_size,
                              hipStream_t stream) {
    const float* x       = (const float*)d_in[0];
    const float* wq_w    = (const float*)d_in[2];
    const float* wq_b    = (const float*)d_in[3];
    const float* wk_w    = (const float*)d_in[4];
    const float* wk_b    = (const float*)d_in[5];
    const float* wv_w    = (const float*)d_in[6];
    const float* wv_b    = (const float*)d_in[7];
    const float* dense_w = (const float*)d_in[8];
    const float* dense_b = (const float*)d_in[9];
    const float* gamma1  = (const float*)d_in[10];
    const float* beta1   = (const float*)d_in[11];
    const float* gamma2  = (const float*)d_in[12];
    const float* beta2   = (const float*)d_in[13];
    const float* fc_w    = (const float*)d_in[14];
    const float* proj_w  = (const float*)d_in[15];
    float* out = (float*)d_out;

    bf16* ws = (bf16*)d_ws;
    const size_t M1 = (size_t)1 << 20;
    bf16* xn   = ws;               // -> h -> hn in place
    bf16* qb   = ws + 4 * M1;
    bf16* kb   = ws + 8 * M1;
    bf16* vb   = ws + 12 * M1;
    bf16* ctx  = ws + 16 * M1;
    bf16* ff1  = qb;               // 16M elems overlay
    bf16* wqc  = ws + 20 * M1;
    bf16* wkc  = ws + 21 * M1;
    bf16* wvc  = ws + 22 * M1;
    bf16* wdc  = ws + 23 * M1;
    bf16* fcc  = ws + 24 * M1;
    bf16* prjc = ws + 28 * M1;
    bf16* h = xn, *hn = xn;

    // weight pre-conversion (fp32 -> bf16)
    cvt_w<<<1024, 256, 0, stream>>>((const float4*)wq_w,    (bf16x4*)wqc,  1 << 18);
    cvt_w<<<1024, 256, 0, stream>>>((const float4*)wk_w,    (bf16x4*)wkc,  1 << 18);
    cvt_w<<<1024, 256, 0, stream>>>((const float4*)wv_w,    (bf16x4*)wvc,  1 << 18);
    cvt_w<<<1024, 256, 0, stream>>>((const float4*)dense_w, (bf16x4*)wdc,  1 << 18);
    cvt_w<<<4096, 256, 0, stream>>>((const float4*)fc_w,    (bf16x4*)fcc,  1 << 20);
    cvt_w<<<4096, 256, 0, stream>>>((const float4*)proj_w,  (bf16x4*)prjc, 1 << 20);

    ln_kernel<float><<<TOK, 256, 0, stream>>>(x, gamma1, beta1, xn);
    gemm_bt<0, bf16><<<dim3(8, 32), 256, 0, stream>>>(xn, wqc, wq_b, nullptr, qb,
                                                      TOK, D_MODEL, D_MODEL, 0.125f);
    gemm_bt<0, bf16><<<dim3(8, 32), 256, 0, stream>>>(xn, wkc, wk_b, nullptr, kb,
                                                      TOK, D_MODEL, D_MODEL, 1.0f);
    gemm_bt<0, bf16><<<dim3(8, 32), 256, 0, stream>>>(xn, wvc, wv_b, nullptr, vb,
                                                      TOK, D_MODEL, D_MODEL, 1.0f);
    attn_kernel<<<dim3(16, BB * NH), 256, 0, stream>>>(qb, kb, vb, ctx);
    gemm_bt<1, bf16><<<dim3(8, 32), 256, 0, stream>>>(ctx, wdc, dense_b, xn, h,
                                                      TOK, D_MODEL, D_MODEL, 1.0f);
    ln_kernel<bf16><<<TOK, 256, 0, stream>>>(h, gamma2, beta2, hn);
    gemm_bt<2, bf16><<<dim3(32, 32), 256, 0, stream>>>(hn, fcc, nullptr, nullptr, ff1,
                                                       TOK, FFD, D_MODEL, 1.0f);
    gemm_bt<3, float><<<dim3(8, 32), 256, 0, stream>>>(ff1, prjc, nullptr, hn, out,
                                                       TOK, D_MODEL, FFD, 1.0f);
}

// Round 9
// 414.360 us; speedup vs baseline: 1.6013x; 1.1539x over previous
//
#include <hip/hip_runtime.h>
#include <math.h>

typedef __bf16 bf16;
typedef __attribute__((ext_vector_type(2))) __bf16 bf16x2;
typedef __attribute__((ext_vector_type(4))) __bf16 bf16x4;
typedef __attribute__((ext_vector_type(8))) __bf16 bf16x8;
typedef __attribute__((ext_vector_type(4))) float f32x4;

#define D_MODEL 1024
#define NH 16
#define DP 64
#define BB 2
#define SEQ 2048
#define TOK 4096   // B*S
#define FFD 4096
#define AST 72     // attn LDS row stride (elems): mult-8 (b128 align), 4-bank row shift

// ---- async global->LDS (wave-uniform LDS base + lane*16, m97 pattern) ----
__device__ __forceinline__ void async16(bf16* lds, const bf16* g) {
    __builtin_amdgcn_global_load_lds(
        (__attribute__((address_space(1))) void*)g,
        (__attribute__((address_space(3))) void*)lds, 16, 0, 0);
}

__device__ __forceinline__ f32x4 mfma16(bf16x8 a, bf16x8 b, f32x4 c) {
    return __builtin_amdgcn_mfma_f32_16x16x32_bf16(a, b, c, 0, 0, 0);
}

// ================= fp32 -> bf16 weight pre-conversion ======================
__global__ __launch_bounds__(256) void cvt_w(
    const float4* __restrict__ in, bf16x4* __restrict__ out, int n4)
{
    const int i = blockIdx.x * 256 + threadIdx.x;
    if (i >= n4) return;
    const float4 v = in[i];
    bf16x4 o; o[0] = (bf16)v.x; o[1] = (bf16)v.y; o[2] = (bf16)v.z; o[3] = (bf16)v.w;
    out[i] = o;
}

// ======================= LayerNorm (unbiased std, eps on std) ==============
template<typename TIN>
__global__ __launch_bounds__(256) void ln_kernel(
    const TIN* __restrict__ in, const float* __restrict__ g,
    const float* __restrict__ be, bf16* __restrict__ out)
{
    const size_t row = blockIdx.x;
    const int t = threadIdx.x;
    const TIN* x = in + row * D_MODEL;

    float v0, v1, v2, v3;
    if constexpr (sizeof(TIN) == 4) {
        const float4 xv = *(const float4*)(x + t * 4);
        v0 = xv.x; v1 = xv.y; v2 = xv.z; v3 = xv.w;
    } else {
        const bf16x4 xv = *(const bf16x4*)(x + t * 4);
        v0 = (float)xv[0]; v1 = (float)xv[1]; v2 = (float)xv[2]; v3 = (float)xv[3];
    }
    float s  = v0 + v1 + v2 + v3;
    float ss = v0*v0 + v1*v1 + v2*v2 + v3*v3;
    #pragma unroll
    for (int off = 32; off > 0; off >>= 1) {
        s  += __shfl_down(s, off);
        ss += __shfl_down(ss, off);
    }
    __shared__ float rs[4], rss[4];
    if ((t & 63) == 0) { rs[t >> 6] = s; rss[t >> 6] = ss; }
    __syncthreads();
    const float S  = rs[0] + rs[1] + rs[2] + rs[3];
    const float SS = rss[0] + rss[1] + rss[2] + rss[3];
    const float mean = S * (1.0f / 1024.0f);
    const float var  = fmaxf((SS - S * mean) * (1.0f / 1023.0f), 0.0f);
    const float inv  = 1.0f / (sqrtf(var) + 1e-6f);

    const float4 gv = *(const float4*)(g  + t * 4);
    const float4 bv = *(const float4*)(be + t * 4);
    bf16x4 ov;
    ov[0] = (bf16)(gv.x * ((v0 - mean) * inv) + bv.x);
    ov[1] = (bf16)(gv.y * ((v1 - mean) * inv) + bv.y);
    ov[2] = (bf16)(gv.z * ((v2 - mean) * inv) + bv.z);
    ov[3] = (bf16)(gv.w * ((v3 - mean) * inv) + bv.w);
    *(bf16x4*)(out + row * D_MODEL + t * 4) = ov;
}

// ============ NT GEMM: C[m,n] = sum_k A[m,k]*W[n,k], A,W bf16 ==============
// EPI 1: +bias +res -> C   EPI 2: exact gelu -> C   EPI 3: +res -> C
template<int EPI, typename TOUT>
__global__ __launch_bounds__(256, 2) void gemm_bt(
    const bf16* __restrict__ A, const bf16* __restrict__ W,
    const float* __restrict__ bias, const bf16* res,
    TOUT* C, int M, int N, int K, float scale)
{
    __shared__ __align__(16) bf16 As[128 * 32];
    __shared__ __align__(16) bf16 Bs[128 * 32];
    const int t = threadIdx.x;
    const int w = t >> 6, lane = t & 63;
    const int fr = lane & 15, quad = lane >> 4;
    const int m0 = blockIdx.y * 128, n0 = blockIdx.x * 128;
    const int wm = (w >> 1) * 64, wn = (w & 1) * 64;

    const f32x4 z = {0.f, 0.f, 0.f, 0.f};
    f32x4 acc[4][4];
    #pragma unroll
    for (int i = 0; i < 4; ++i)
        #pragma unroll
        for (int j = 0; j < 4; ++j) acc[i][j] = z;

    const int nk = K >> 5;
    for (int kt = 0; kt < nk; ++kt) {
        const int k0 = kt << 5;
        #pragma unroll
        for (int call = 0; call < 2; ++call) {
            const int c = call * 256 + t;
            const int row = c >> 2, sub = c & 3;
            async16(&As[(size_t)(call * 256 + w * 64) * 8],
                    A + (size_t)(m0 + row) * K + k0 + sub * 8);
            async16(&Bs[(size_t)(call * 256 + w * 64) * 8],
                    W + (size_t)(n0 + row) * K + k0 + sub * 8);
        }
        __syncthreads();
        bf16x8 af[4], bfr[4];
        #pragma unroll
        for (int i = 0; i < 4; ++i)
            af[i] = *(const bf16x8*)&As[(wm + i * 16 + fr) * 32 + quad * 8];
        #pragma unroll
        for (int j = 0; j < 4; ++j)
            bfr[j] = *(const bf16x8*)&Bs[(wn + j * 16 + fr) * 32 + quad * 8];
        #pragma unroll
        for (int i = 0; i < 4; ++i)
            #pragma unroll
            for (int j = 0; j < 4; ++j)
                acc[i][j] = mfma16(af[i], bfr[j], acc[i][j]);
        __syncthreads();
    }

    // Epilogue. C/D layout (m89): col = lane&15, row = quad*4 + reg.
    #pragma unroll
    for (int i = 0; i < 4; ++i) {
        #pragma unroll
        for (int j = 0; j < 4; ++j) {
            #pragma unroll
            for (int r = 0; r < 4; ++r) {
                const int m = m0 + wm + i * 16 + quad * 4 + r;
                const int n = n0 + wn + j * 16 + fr;
                float v = acc[i][j][r];
                if (EPI == 1) {
                    v += bias[n];
                    v += (float)res[(size_t)m * N + n];
                    C[(size_t)m * N + n] = (TOUT)v;
                } else if (EPI == 2) {
                    v = 0.5f * v * (1.0f + erff(v * 0.70710678118f));
                    C[(size_t)m * N + n] = (TOUT)v;
                } else {
                    v += (float)res[(size_t)m * N + n];
                    C[(size_t)m * N + n] = (TOUT)v;
                }
            }
        }
    }
}

// ============ Fused QKV GEMM: one dispatch, grid (24, 32) ==================
// blockIdx.x>>3 selects {Q,K,V}; epilogue (v+bias)*scale -> [B,H,S,DP]
__global__ __launch_bounds__(256, 2) void gemm_qkv(
    const bf16* __restrict__ A,
    const bf16* __restrict__ wq, const bf16* __restrict__ wk,
    const bf16* __restrict__ wvv,
    const float* __restrict__ bq, const float* __restrict__ bk,
    const float* __restrict__ bv,
    bf16* __restrict__ outq, bf16* __restrict__ outk, bf16* __restrict__ outv)
{
    const int sel = blockIdx.x >> 3;
    const bf16* W = (sel == 0) ? wq : ((sel == 1) ? wk : wvv);
    const float* bias = (sel == 0) ? bq : ((sel == 1) ? bk : bv);
    bf16* C = (sel == 0) ? outq : ((sel == 1) ? outk : outv);
    const float scale = (sel == 0) ? 0.125f : 1.0f;
    const int K = D_MODEL;

    __shared__ __align__(16) bf16 As[128 * 32];
    __shared__ __align__(16) bf16 Bs[128 * 32];
    const int t = threadIdx.x;
    const int w = t >> 6, lane = t & 63;
    const int fr = lane & 15, quad = lane >> 4;
    const int m0 = blockIdx.y * 128, n0 = (blockIdx.x & 7) * 128;
    const int wm = (w >> 1) * 64, wn = (w & 1) * 64;

    const f32x4 z = {0.f, 0.f, 0.f, 0.f};
    f32x4 acc[4][4];
    #pragma unroll
    for (int i = 0; i < 4; ++i)
        #pragma unroll
        for (int j = 0; j < 4; ++j) acc[i][j] = z;

    for (int kt = 0; kt < (D_MODEL >> 5); ++kt) {
        const int k0 = kt << 5;
        #pragma unroll
        for (int call = 0; call < 2; ++call) {
            const int c = call * 256 + t;
            const int row = c >> 2, sub = c & 3;
            async16(&As[(size_t)(call * 256 + w * 64) * 8],
                    A + (size_t)(m0 + row) * K + k0 + sub * 8);
            async16(&Bs[(size_t)(call * 256 + w * 64) * 8],
                    W + (size_t)(n0 + row) * K + k0 + sub * 8);
        }
        __syncthreads();
        bf16x8 af[4], bfr[4];
        #pragma unroll
        for (int i = 0; i < 4; ++i)
            af[i] = *(const bf16x8*)&As[(wm + i * 16 + fr) * 32 + quad * 8];
        #pragma unroll
        for (int j = 0; j < 4; ++j)
            bfr[j] = *(const bf16x8*)&Bs[(wn + j * 16 + fr) * 32 + quad * 8];
        #pragma unroll
        for (int i = 0; i < 4; ++i)
            #pragma unroll
            for (int j = 0; j < 4; ++j)
                acc[i][j] = mfma16(af[i], bfr[j], acc[i][j]);
        __syncthreads();
    }

    #pragma unroll
    for (int i = 0; i < 4; ++i)
        #pragma unroll
        for (int j = 0; j < 4; ++j)
            #pragma unroll
            for (int r = 0; r < 4; ++r) {
                const int m = m0 + wm + i * 16 + quad * 4 + r;
                const int n = n0 + wn + j * 16 + fr;
                const float vv = (acc[i][j][r] + bias[n]) * scale;
                const int b = m >> 11, s = m & 2047, h = n >> 6, d = n & 63;
                C[(((size_t)(b * NH + h)) * SEQ + s) * DP + d] = (bf16)vv;
            }
}

// ======================= Flash attention (causal, pipelined) ===============
// q,k,v: [B*H, S, DP] bf16, q pre-scaled by 1/8. ctx: [B, S, D_MODEL].
// Block handles q-tile pair (x, 31-x): uniform 33 steps. Single barrier/step,
// register prefetch of next K/V tile overlaps the whole compute phase.
__global__ __launch_bounds__(256, 2) void attn_kernel(
    const bf16* __restrict__ q, const bf16* __restrict__ k,
    const bf16* __restrict__ v, bf16* __restrict__ ctx)
{
    __shared__ __align__(16) bf16 Ks[2][64 * AST];   // [buf][key][d] stride 72
    __shared__ __align__(16) bf16 VsT[2][64 * AST];  // [buf][d][key] stride 72
    __shared__ __align__(16) bf16 Ps[4][16 * AST];   // per-wave P
    const int t = threadIdx.x, wv = t >> 6, lane = t & 63;
    const int fr = lane & 15, quad = lane >> 4;
    const int bh = blockIdx.y;
    const size_t base = (size_t)bh * SEQ * DP;
    const int b = bh >> 4, hh = bh & 15;
    const f32x4 z = {0.f, 0.f, 0.f, 0.f};
    // K staging map: thread -> (row = t>>2, d0 = (t&3)*16), 2x b128, coalesced.
    const int krow = t >> 2, kd0 = (t & 3) * 16;
    // V staging map: thread -> key-pair p = t&31, d cols c0..c0+7. Write bank
    // = 4j + p mod 32: 32 consecutive lanes cover 32 banks -> conflict-free.
    const int pp = t & 31, c0 = (t >> 5) * 8;

    for (int half = 0; half < 2; ++half) {
        const int qt = half ? (31 - (int)blockIdx.x) : (int)blockIdx.x;
        const int q0 = qt * 64, qr0 = q0 + wv * 16;
        const int nkt = qt + 1;

        __syncthreads();   // previous half's LDS reads complete

        bf16x8 qf[2];
        #pragma unroll
        for (int c = 0; c < 2; ++c)
            qf[c] = *(const bf16x8*)(q + base + (size_t)(qr0 + fr) * DP + c * 32 + quad * 8);

        // prologue: load tile-0 K/V into registers
        bf16x8 k0r, k1r, v0r, v1r;
        {
            const bf16* kp = k + base + (size_t)krow * DP + kd0;
            k0r = *(const bf16x8*)kp; k1r = *(const bf16x8*)(kp + 8);
            const bf16* vp = v + base + (size_t)(2 * pp) * DP + c0;
            v0r = *(const bf16x8*)vp; v1r = *(const bf16x8*)(vp + DP);
        }

        f32x4 o[4] = {z, z, z, z};
        float mi[4] = {-1e30f, -1e30f, -1e30f, -1e30f};
        float li[4] = {0.f, 0.f, 0.f, 0.f};

        for (int kt = 0; kt < nkt; ++kt) {
            const int cur = kt & 1;
            const int kk0 = kt * 64;
            // stage regs -> LDS (compiler waits vmcnt on the regs here)
            *(bf16x8*)&Ks[cur][krow * AST + kd0]     = k0r;
            *(bf16x8*)&Ks[cur][krow * AST + kd0 + 8] = k1r;
            #pragma unroll
            for (int j = 0; j < 8; ++j) {
                bf16x2 pr; pr[0] = v0r[j]; pr[1] = v1r[j];
                *(bf16x2*)&VsT[cur][(c0 + j) * AST + 2 * pp] = pr;
            }
            __syncthreads();   // staging visible; nothing left outstanding
            // prefetch next tile (in flight across the whole compute phase)
            if (kt + 1 < nkt) {
                const bf16* kp = k + base + (size_t)(kk0 + 64 + krow) * DP + kd0;
                k0r = *(const bf16x8*)kp; k1r = *(const bf16x8*)(kp + 8);
                const bf16* vp = v + base + (size_t)(kk0 + 64 + 2 * pp) * DP + c0;
                v0r = *(const bf16x8*)vp; v1r = *(const bf16x8*)(vp + DP);
            }

            // S = q k^T
            f32x4 sa[4] = {z, z, z, z};
            #pragma unroll
            for (int nb = 0; nb < 4; ++nb)
                #pragma unroll
                for (int c = 0; c < 2; ++c) {
                    const bf16x8 kf = *(const bf16x8*)&Ks[cur][(nb * 16 + fr) * AST + c * 32 + quad * 8];
                    sa[nb] = mfma16(qf[c], kf, sa[nb]);
                }

            float p[4][4], rmax[4];
            #pragma unroll
            for (int r = 0; r < 4; ++r) rmax[r] = -1e30f;
            #pragma unroll
            for (int nb = 0; nb < 4; ++nb)
                #pragma unroll
                for (int r = 0; r < 4; ++r) {
                    const int key = kk0 + nb * 16 + fr;
                    const int qrow = qr0 + quad * 4 + r;
                    float sv = sa[nb][r];
                    if (key > qrow) sv += -1e9f;
                    p[nb][r] = sv;
                    rmax[r] = fmaxf(rmax[r], sv);
                }
            #pragma unroll
            for (int off = 1; off < 16; off <<= 1)
                #pragma unroll
                for (int r = 0; r < 4; ++r)
                    rmax[r] = fmaxf(rmax[r], __shfl_xor(rmax[r], off));

            float alpha[4], psum[4];
            #pragma unroll
            for (int r = 0; r < 4; ++r) {
                const float nm = fmaxf(mi[r], rmax[r]);
                alpha[r] = __expf(mi[r] - nm);
                mi[r] = nm;
                float ps = 0.f;
                #pragma unroll
                for (int nb = 0; nb < 4; ++nb) {
                    const float e = __expf(p[nb][r] - nm);
                    p[nb][r] = e;
                    ps += e;
                }
                psum[r] = ps;
            }
            #pragma unroll
            for (int off = 1; off < 16; off <<= 1)
                #pragma unroll
                for (int r = 0; r < 4; ++r)
                    psum[r] += __shfl_xor(psum[r], off);
            #pragma unroll
            for (int r = 0; r < 4; ++r) li[r] = li[r] * alpha[r] + psum[r];
            #pragma unroll
            for (int db = 0; db < 4; ++db)
                #pragma unroll
                for (int r = 0; r < 4; ++r) o[db][r] *= alpha[r];

            // P: C-layout -> wave-private LDS (same-wave DS ordering)
            #pragma unroll
            for (int nb = 0; nb < 4; ++nb)
                #pragma unroll
                for (int r = 0; r < 4; ++r)
                    Ps[wv][(quad * 4 + r) * AST + nb * 16 + fr] = (bf16)p[nb][r];

            // PV: A = P (A-layout), B = V^T rows (b128, conflict-free)
            bf16x8 pf[2];
            #pragma unroll
            for (int c = 0; c < 2; ++c)
                pf[c] = *(const bf16x8*)&Ps[wv][fr * AST + c * 32 + quad * 8];
            #pragma unroll
            for (int db = 0; db < 4; ++db)
                #pragma unroll
                for (int c = 0; c < 2; ++c) {
                    const bf16x8 vf = *(const bf16x8*)&VsT[cur][(db * 16 + fr) * AST + c * 32 + quad * 8];
                    o[db] = mfma16(pf[c], vf, o[db]);
                }
        }

        #pragma unroll
        for (int db = 0; db < 4; ++db)
            #pragma unroll
            for (int r = 0; r < 4; ++r) {
                const int qrow = qr0 + quad * 4 + r;
                const int d = db * 16 + fr;
                ctx[((size_t)(b * SEQ + qrow)) * D_MODEL + hh * DP + d] =
                    (bf16)(o[db][r] / li[r]);
            }
    }
}

// ======================= launcher ==========================================
// fp32 inputs, fp32 output. Internal bf16. Arena (bf16 elems, 64 MiB):
//   [0,4M): xn -> h -> hn   [4,8M): qb  [8,12M): kb  [12,16M): vb  [16,20M): ctx
//   ff1 = [4,20M) overlay   [20,24M): wq/wk/wv/wd bf16   [24,28M): fc  [28,32M): proj
extern "C" void kernel_launch(void* const* d_in, const int* in_sizes, int n_in,
                              void* d_out, int out_size, void* d_ws, size_t ws_size,
                              hipStream_t stream) {
    const float* x       = (const float*)d_in[0];
    const float* wq_w    = (const float*)d_in[2];
    const float* wq_b    = (const float*)d_in[3];
    const float* wk_w    = (const float*)d_in[4];
    const float* wk_b    = (const float*)d_in[5];
    const float* wv_w    = (const float*)d_in[6];
    const float* wv_b    = (const float*)d_in[7];
    const float* dense_w = (const float*)d_in[8];
    const float* dense_b = (const float*)d_in[9];
    const float* gamma1  = (const float*)d_in[10];
    const float* beta1   = (const float*)d_in[11];
    const float* gamma2  = (const float*)d_in[12];
    const float* beta2   = (const float*)d_in[13];
    const float* fc_w    = (const float*)d_in[14];
    const float* proj_w  = (const float*)d_in[15];
    float* out = (float*)d_out;

    bf16* ws = (bf16*)d_ws;
    const size_t M1 = (size_t)1 << 20;
    bf16* xn   = ws;               // -> h -> hn in place
    bf16* qb   = ws + 4 * M1;
    bf16* kb   = ws + 8 * M1;
    bf16* vb   = ws + 12 * M1;
    bf16* ctx  = ws + 16 * M1;
    bf16* ff1  = qb;               // 16M elems overlay
    bf16* wqc  = ws + 20 * M1;
    bf16* wkc  = ws + 21 * M1;
    bf16* wvc  = ws + 22 * M1;
    bf16* wdc  = ws + 23 * M1;
    bf16* fcc  = ws + 24 * M1;
    bf16* prjc = ws + 28 * M1;
    bf16* h = xn, *hn = xn;

    // weight pre-conversion (fp32 -> bf16)
    cvt_w<<<1024, 256, 0, stream>>>((const float4*)wq_w,    (bf16x4*)wqc,  1 << 18);
    cvt_w<<<1024, 256, 0, stream>>>((const float4*)wk_w,    (bf16x4*)wkc,  1 << 18);
    cvt_w<<<1024, 256, 0, stream>>>((const float4*)wv_w,    (bf16x4*)wvc,  1 << 18);
    cvt_w<<<1024, 256, 0, stream>>>((const float4*)dense_w, (bf16x4*)wdc,  1 << 18);
    cvt_w<<<4096, 256, 0, stream>>>((const float4*)fc_w,    (bf16x4*)fcc,  1 << 20);
    cvt_w<<<4096, 256, 0, stream>>>((const float4*)proj_w,  (bf16x4*)prjc, 1 << 20);

    ln_kernel<float><<<TOK, 256, 0, stream>>>(x, gamma1, beta1, xn);
    gemm_qkv<<<dim3(24, 32), 256, 0, stream>>>(xn, wqc, wkc, wvc,
                                               wq_b, wk_b, wv_b, qb, kb, vb);
    attn_kernel<<<dim3(16, BB * NH), 256, 0, stream>>>(qb, kb, vb, ctx);
    gemm_bt<1, bf16><<<dim3(8, 32), 256, 0, stream>>>(ctx, wdc, dense_b, xn, h,
                                                      TOK, D_MODEL, D_MODEL, 1.0f);
    ln_kernel<bf16><<<TOK, 256, 0, stream>>>(h, gamma2, beta2, hn);
    gemm_bt<2, bf16><<<dim3(32, 32), 256, 0, stream>>>(hn, fcc, nullptr, nullptr, ff1,
                                                       TOK, FFD, D_MODEL, 1.0f);
    gemm_bt<3, float><<<dim3(8, 32), 256, 0, stream>>>(ff1, prjc, nullptr, hn, out,
                                                       TOK, D_MODEL, FFD, 1.0f);
}

// Round 10
// 394.374 us; speedup vs baseline: 1.6825x; 1.0507x over previous
//
#include <hip/hip_runtime.h>
#include <math.h>

typedef __bf16 bf16;
typedef __attribute__((ext_vector_type(2))) __bf16 bf16x2;
typedef __attribute__((ext_vector_type(4))) __bf16 bf16x4;
typedef __attribute__((ext_vector_type(8))) __bf16 bf16x8;
typedef __attribute__((ext_vector_type(4))) float f32x4;

#define D_MODEL 1024
#define NH 16
#define DP 64
#define BB 2
#define SEQ 2048
#define TOK 4096   // B*S
#define FFD 4096
#define AST 72     // attn LDS row stride (elems)

// ---- async global->LDS (wave-uniform LDS base + lane*16, m97 pattern) ----
__device__ __forceinline__ void async16(bf16* lds, const bf16* g) {
    __builtin_amdgcn_global_load_lds(
        (__attribute__((address_space(1))) void*)g,
        (__attribute__((address_space(3))) void*)lds, 16, 0, 0);
}

__device__ __forceinline__ f32x4 mfma16(bf16x8 a, bf16x8 b, f32x4 c) {
    return __builtin_amdgcn_mfma_f32_16x16x32_bf16(a, b, c, 0, 0, 0);
}

// ============ fused fp32 -> bf16 weight pre-conversion (one dispatch) ======
// segments: 4 x 2^18 float4 (wq,wk,wv,wd) then 2 x 2^20 float4 (fc, proj)
struct CvtArgs {
    const float4* in[6];
    bf16x4* out[6];
};
__global__ __launch_bounds__(256) void cvt_all(CvtArgs a)
{
    const int i = blockIdx.x * 256 + threadIdx.x;   // [0, 3*2^20)
    int seg, idx;
    if (i < (1 << 20)) { seg = i >> 18; idx = i & ((1 << 18) - 1); }
    else {
        const int j = i - (1 << 20);
        seg = 4 + (j >> 20); idx = j & ((1 << 20) - 1);
    }
    const float4 v = a.in[seg][idx];
    bf16x4 o; o[0] = (bf16)v.x; o[1] = (bf16)v.y; o[2] = (bf16)v.z; o[3] = (bf16)v.w;
    a.out[seg][idx] = o;
}

// ======================= LayerNorm (unbiased std, eps on std) ==============
template<typename TIN>
__global__ __launch_bounds__(256) void ln_kernel(
    const TIN* __restrict__ in, const float* __restrict__ g,
    const float* __restrict__ be, bf16* __restrict__ out)
{
    const size_t row = blockIdx.x;
    const int t = threadIdx.x;
    const TIN* x = in + row * D_MODEL;

    float v0, v1, v2, v3;
    if constexpr (sizeof(TIN) == 4) {
        const float4 xv = *(const float4*)(x + t * 4);
        v0 = xv.x; v1 = xv.y; v2 = xv.z; v3 = xv.w;
    } else {
        const bf16x4 xv = *(const bf16x4*)(x + t * 4);
        v0 = (float)xv[0]; v1 = (float)xv[1]; v2 = (float)xv[2]; v3 = (float)xv[3];
    }
    float s  = v0 + v1 + v2 + v3;
    float ss = v0*v0 + v1*v1 + v2*v2 + v3*v3;
    #pragma unroll
    for (int off = 32; off > 0; off >>= 1) {
        s  += __shfl_down(s, off);
        ss += __shfl_down(ss, off);
    }
    __shared__ float rs[4], rss[4];
    if ((t & 63) == 0) { rs[t >> 6] = s; rss[t >> 6] = ss; }
    __syncthreads();
    const float S  = rs[0] + rs[1] + rs[2] + rs[3];
    const float SS = rss[0] + rss[1] + rss[2] + rss[3];
    const float mean = S * (1.0f / 1024.0f);
    const float var  = fmaxf((SS - S * mean) * (1.0f / 1023.0f), 0.0f);
    const float inv  = 1.0f / (sqrtf(var) + 1e-6f);

    const float4 gv = *(const float4*)(g  + t * 4);
    const float4 bv = *(const float4*)(be + t * 4);
    bf16x4 ov;
    ov[0] = (bf16)(gv.x * ((v0 - mean) * inv) + bv.x);
    ov[1] = (bf16)(gv.y * ((v1 - mean) * inv) + bv.y);
    ov[2] = (bf16)(gv.z * ((v2 - mean) * inv) + bv.z);
    ov[3] = (bf16)(gv.w * ((v3 - mean) * inv) + bv.w);
    *(bf16x4*)(out + row * D_MODEL + t * 4) = ov;
}

// ====== NT GEMM 128x128: C[m,n] = sum_k A[m,k]*W[n,k] (fc: gelu) ===========
template<int EPI, typename TOUT>
__global__ __launch_bounds__(256, 2) void gemm_bt(
    const bf16* __restrict__ A, const bf16* __restrict__ W,
    const float* __restrict__ bias, const bf16* res,
    TOUT* C, int M, int N, int K, float scale)
{
    __shared__ __align__(16) bf16 As[128 * 32];
    __shared__ __align__(16) bf16 Bs[128 * 32];
    const int t = threadIdx.x;
    const int w = t >> 6, lane = t & 63;
    const int fr = lane & 15, quad = lane >> 4;
    const int m0 = blockIdx.y * 128, n0 = blockIdx.x * 128;
    const int wm = (w >> 1) * 64, wn = (w & 1) * 64;

    const f32x4 z = {0.f, 0.f, 0.f, 0.f};
    f32x4 acc[4][4];
    #pragma unroll
    for (int i = 0; i < 4; ++i)
        #pragma unroll
        for (int j = 0; j < 4; ++j) acc[i][j] = z;

    const int nk = K >> 5;
    for (int kt = 0; kt < nk; ++kt) {
        const int k0 = kt << 5;
        #pragma unroll
        for (int call = 0; call < 2; ++call) {
            const int c = call * 256 + t;
            const int row = c >> 2, sub = c & 3;
            async16(&As[(size_t)(call * 256 + w * 64) * 8],
                    A + (size_t)(m0 + row) * K + k0 + sub * 8);
            async16(&Bs[(size_t)(call * 256 + w * 64) * 8],
                    W + (size_t)(n0 + row) * K + k0 + sub * 8);
        }
        __syncthreads();
        bf16x8 af[4], bfr[4];
        #pragma unroll
        for (int i = 0; i < 4; ++i)
            af[i] = *(const bf16x8*)&As[(wm + i * 16 + fr) * 32 + quad * 8];
        #pragma unroll
        for (int j = 0; j < 4; ++j)
            bfr[j] = *(const bf16x8*)&Bs[(wn + j * 16 + fr) * 32 + quad * 8];
        #pragma unroll
        for (int i = 0; i < 4; ++i)
            #pragma unroll
            for (int j = 0; j < 4; ++j)
                acc[i][j] = mfma16(af[i], bfr[j], acc[i][j]);
        __syncthreads();
    }

    // Epilogue. C/D layout (m89): col = lane&15, row = quad*4 + reg.
    #pragma unroll
    for (int i = 0; i < 4; ++i) {
        #pragma unroll
        for (int j = 0; j < 4; ++j) {
            #pragma unroll
            for (int r = 0; r < 4; ++r) {
                const int m = m0 + wm + i * 16 + quad * 4 + r;
                const int n = n0 + wn + j * 16 + fr;
                float v = acc[i][j][r];
                if (EPI == 1) {
                    v += bias[n];
                    v += (float)res[(size_t)m * N + n];
                    C[(size_t)m * N + n] = (TOUT)v;
                } else if (EPI == 2) {
                    v = 0.5f * v * (1.0f + erff(v * 0.70710678118f));
                    C[(size_t)m * N + n] = (TOUT)v;
                } else {
                    v += (float)res[(size_t)m * N + n];
                    C[(size_t)m * N + n] = (TOUT)v;
                }
            }
        }
    }
}

// ====== NT GEMM 128x64 (N=1024 shapes: dense EPI1, proj EPI3) ==============
// Grid (N/64, M/128) = 512 blocks = 2/CU: restores inter-block overlap.
// Wave tile 64x32: acc[4][2].
template<int EPI, typename TOUT>
__global__ __launch_bounds__(256, 2) void gemm_bt64(
    const bf16* __restrict__ A, const bf16* __restrict__ W,
    const float* __restrict__ bias, const bf16* res,
    TOUT* C, int M, int N, int K)
{
    __shared__ __align__(16) bf16 As[128 * 32];
    __shared__ __align__(16) bf16 Bs[64 * 32];
    const int t = threadIdx.x;
    const int w = t >> 6, lane = t & 63;
    const int fr = lane & 15, quad = lane >> 4;
    const int m0 = blockIdx.y * 128, n0 = blockIdx.x * 64;
    const int wm = (w >> 1) * 64, wn = (w & 1) * 32;

    const f32x4 z = {0.f, 0.f, 0.f, 0.f};
    f32x4 acc[4][2];
    #pragma unroll
    for (int i = 0; i < 4; ++i)
        #pragma unroll
        for (int j = 0; j < 2; ++j) acc[i][j] = z;

    const int nk = K >> 5;
    for (int kt = 0; kt < nk; ++kt) {
        const int k0 = kt << 5;
        #pragma unroll
        for (int call = 0; call < 2; ++call) {
            const int c = call * 256 + t;
            const int row = c >> 2, sub = c & 3;
            async16(&As[(size_t)(call * 256 + w * 64) * 8],
                    A + (size_t)(m0 + row) * K + k0 + sub * 8);
        }
        {   // B tile 64x32: one async16/thread
            const int row = t >> 2, sub = t & 3;
            async16(&Bs[(size_t)(w * 64) * 8],
                    W + (size_t)(n0 + row) * K + k0 + sub * 8);
        }
        __syncthreads();
        bf16x8 af[4], bfr[2];
        #pragma unroll
        for (int i = 0; i < 4; ++i)
            af[i] = *(const bf16x8*)&As[(wm + i * 16 + fr) * 32 + quad * 8];
        #pragma unroll
        for (int j = 0; j < 2; ++j)
            bfr[j] = *(const bf16x8*)&Bs[(wn + j * 16 + fr) * 32 + quad * 8];
        #pragma unroll
        for (int i = 0; i < 4; ++i)
            #pragma unroll
            for (int j = 0; j < 2; ++j)
                acc[i][j] = mfma16(af[i], bfr[j], acc[i][j]);
        __syncthreads();
    }

    #pragma unroll
    for (int i = 0; i < 4; ++i) {
        #pragma unroll
        for (int j = 0; j < 2; ++j) {
            #pragma unroll
            for (int r = 0; r < 4; ++r) {
                const int m = m0 + wm + i * 16 + quad * 4 + r;
                const int n = n0 + wn + j * 16 + fr;
                float v = acc[i][j][r];
                if (EPI == 1) {
                    v += bias[n];
                    v += (float)res[(size_t)m * N + n];
                    C[(size_t)m * N + n] = (TOUT)v;
                } else {
                    v += (float)res[(size_t)m * N + n];
                    C[(size_t)m * N + n] = (TOUT)v;
                }
            }
        }
    }
}

// ============ Fused QKV GEMM: one dispatch, grid (24, 32) ==================
__global__ __launch_bounds__(256, 2) void gemm_qkv(
    const bf16* __restrict__ A,
    const bf16* __restrict__ wq, const bf16* __restrict__ wk,
    const bf16* __restrict__ wvv,
    const float* __restrict__ bq, const float* __restrict__ bk,
    const float* __restrict__ bv,
    bf16* __restrict__ outq, bf16* __restrict__ outk, bf16* __restrict__ outv)
{
    const int sel = blockIdx.x >> 3;
    const bf16* W = (sel == 0) ? wq : ((sel == 1) ? wk : wvv);
    const float* bias = (sel == 0) ? bq : ((sel == 1) ? bk : bv);
    bf16* C = (sel == 0) ? outq : ((sel == 1) ? outk : outv);
    const float scale = (sel == 0) ? 0.125f : 1.0f;
    const int K = D_MODEL;

    __shared__ __align__(16) bf16 As[128 * 32];
    __shared__ __align__(16) bf16 Bs[128 * 32];
    const int t = threadIdx.x;
    const int w = t >> 6, lane = t & 63;
    const int fr = lane & 15, quad = lane >> 4;
    const int m0 = blockIdx.y * 128, n0 = (blockIdx.x & 7) * 128;
    const int wm = (w >> 1) * 64, wn = (w & 1) * 64;

    const f32x4 z = {0.f, 0.f, 0.f, 0.f};
    f32x4 acc[4][4];
    #pragma unroll
    for (int i = 0; i < 4; ++i)
        #pragma unroll
        for (int j = 0; j < 4; ++j) acc[i][j] = z;

    for (int kt = 0; kt < (D_MODEL >> 5); ++kt) {
        const int k0 = kt << 5;
        #pragma unroll
        for (int call = 0; call < 2; ++call) {
            const int c = call * 256 + t;
            const int row = c >> 2, sub = c & 3;
            async16(&As[(size_t)(call * 256 + w * 64) * 8],
                    A + (size_t)(m0 + row) * K + k0 + sub * 8);
            async16(&Bs[(size_t)(call * 256 + w * 64) * 8],
                    W + (size_t)(n0 + row) * K + k0 + sub * 8);
        }
        __syncthreads();
        bf16x8 af[4], bfr[4];
        #pragma unroll
        for (int i = 0; i < 4; ++i)
            af[i] = *(const bf16x8*)&As[(wm + i * 16 + fr) * 32 + quad * 8];
        #pragma unroll
        for (int j = 0; j < 4; ++j)
            bfr[j] = *(const bf16x8*)&Bs[(wn + j * 16 + fr) * 32 + quad * 8];
        #pragma unroll
        for (int i = 0; i < 4; ++i)
            #pragma unroll
            for (int j = 0; j < 4; ++j)
                acc[i][j] = mfma16(af[i], bfr[j], acc[i][j]);
        __syncthreads();
    }

    #pragma unroll
    for (int i = 0; i < 4; ++i)
        #pragma unroll
        for (int j = 0; j < 4; ++j)
            #pragma unroll
            for (int r = 0; r < 4; ++r) {
                const int m = m0 + wm + i * 16 + quad * 4 + r;
                const int n = n0 + wn + j * 16 + fr;
                const float vv = (acc[i][j][r] + bias[n]) * scale;
                const int b = m >> 11, s = m & 2047, h = n >> 6, d = n & 63;
                C[(((size_t)(b * NH + h)) * SEQ + s) * DP + d] = (bf16)vv;
            }
}

// ======================= Flash attention (causal, pipelined) ===============
__global__ __launch_bounds__(256, 2) void attn_kernel(
    const bf16* __restrict__ q, const bf16* __restrict__ k,
    const bf16* __restrict__ v, bf16* __restrict__ ctx)
{
    __shared__ __align__(16) bf16 Ks[2][64 * AST];
    __shared__ __align__(16) bf16 VsT[2][64 * AST];
    __shared__ __align__(16) bf16 Ps[4][16 * AST];
    const int t = threadIdx.x, wv = t >> 6, lane = t & 63;
    const int fr = lane & 15, quad = lane >> 4;
    const int bh = blockIdx.y;
    const size_t base = (size_t)bh * SEQ * DP;
    const int b = bh >> 4, hh = bh & 15;
    const f32x4 z = {0.f, 0.f, 0.f, 0.f};
    const int krow = t >> 2, kd0 = (t & 3) * 16;
    const int pp = t & 31, c0 = (t >> 5) * 8;

    for (int half = 0; half < 2; ++half) {
        const int qt = half ? (31 - (int)blockIdx.x) : (int)blockIdx.x;
        const int q0 = qt * 64, qr0 = q0 + wv * 16;
        const int nkt = qt + 1;

        __syncthreads();

        bf16x8 qf[2];
        #pragma unroll
        for (int c = 0; c < 2; ++c)
            qf[c] = *(const bf16x8*)(q + base + (size_t)(qr0 + fr) * DP + c * 32 + quad * 8);

        bf16x8 k0r, k1r, v0r, v1r;
        {
            const bf16* kp = k + base + (size_t)krow * DP + kd0;
            k0r = *(const bf16x8*)kp; k1r = *(const bf16x8*)(kp + 8);
            const bf16* vp = v + base + (size_t)(2 * pp) * DP + c0;
            v0r = *(const bf16x8*)vp; v1r = *(const bf16x8*)(vp + DP);
        }

        f32x4 o[4] = {z, z, z, z};
        float mi[4] = {-1e30f, -1e30f, -1e30f, -1e30f};
        float li[4] = {0.f, 0.f, 0.f, 0.f};

        for (int kt = 0; kt < nkt; ++kt) {
            const int cur = kt & 1;
            const int kk0 = kt * 64;
            *(bf16x8*)&Ks[cur][krow * AST + kd0]     = k0r;
            *(bf16x8*)&Ks[cur][krow * AST + kd0 + 8] = k1r;
            #pragma unroll
            for (int j = 0; j < 8; ++j) {
                bf16x2 pr; pr[0] = v0r[j]; pr[1] = v1r[j];
                *(bf16x2*)&VsT[cur][(c0 + j) * AST + 2 * pp] = pr;
            }
            __syncthreads();
            if (kt + 1 < nkt) {
                const bf16* kp = k + base + (size_t)(kk0 + 64 + krow) * DP + kd0;
                k0r = *(const bf16x8*)kp; k1r = *(const bf16x8*)(kp + 8);
                const bf16* vp = v + base + (size_t)(kk0 + 64 + 2 * pp) * DP + c0;
                v0r = *(const bf16x8*)vp; v1r = *(const bf16x8*)(vp + DP);
            }

            f32x4 sa[4] = {z, z, z, z};
            #pragma unroll
            for (int nb = 0; nb < 4; ++nb)
                #pragma unroll
                for (int c = 0; c < 2; ++c) {
                    const bf16x8 kf = *(const bf16x8*)&Ks[cur][(nb * 16 + fr) * AST + c * 32 + quad * 8];
                    sa[nb] = mfma16(qf[c], kf, sa[nb]);
                }

            float p[4][4], rmax[4];
            #pragma unroll
            for (int r = 0; r < 4; ++r) rmax[r] = -1e30f;
            #pragma unroll
            for (int nb = 0; nb < 4; ++nb)
                #pragma unroll
                for (int r = 0; r < 4; ++r) {
                    const int key = kk0 + nb * 16 + fr;
                    const int qrow = qr0 + quad * 4 + r;
                    float sv = sa[nb][r];
                    if (key > qrow) sv += -1e9f;
                    p[nb][r] = sv;
                    rmax[r] = fmaxf(rmax[r], sv);
                }
            #pragma unroll
            for (int off = 1; off < 16; off <<= 1)
                #pragma unroll
                for (int r = 0; r < 4; ++r)
                    rmax[r] = fmaxf(rmax[r], __shfl_xor(rmax[r], off));

            float alpha[4], psum[4];
            #pragma unroll
            for (int r = 0; r < 4; ++r) {
                const float nm = fmaxf(mi[r], rmax[r]);
                alpha[r] = __expf(mi[r] - nm);
                mi[r] = nm;
                float ps = 0.f;
                #pragma unroll
                for (int nb = 0; nb < 4; ++nb) {
                    const float e = __expf(p[nb][r] - nm);
                    p[nb][r] = e;
                    ps += e;
                }
                psum[r] = ps;
            }
            #pragma unroll
            for (int off = 1; off < 16; off <<= 1)
                #pragma unroll
                for (int r = 0; r < 4; ++r)
                    psum[r] += __shfl_xor(psum[r], off);
            #pragma unroll
            for (int r = 0; r < 4; ++r) li[r] = li[r] * alpha[r] + psum[r];
            #pragma unroll
            for (int db = 0; db < 4; ++db)
                #pragma unroll
                for (int r = 0; r < 4; ++r) o[db][r] *= alpha[r];

            #pragma unroll
            for (int nb = 0; nb < 4; ++nb)
                #pragma unroll
                for (int r = 0; r < 4; ++r)
                    Ps[wv][(quad * 4 + r) * AST + nb * 16 + fr] = (bf16)p[nb][r];

            bf16x8 pf[2];
            #pragma unroll
            for (int c = 0; c < 2; ++c)
                pf[c] = *(const bf16x8*)&Ps[wv][fr * AST + c * 32 + quad * 8];
            #pragma unroll
            for (int db = 0; db < 4; ++db)
                #pragma unroll
                for (int c = 0; c < 2; ++c) {
                    const bf16x8 vf = *(const bf16x8*)&VsT[cur][(db * 16 + fr) * AST + c * 32 + quad * 8];
                    o[db] = mfma16(pf[c], vf, o[db]);
                }
        }

        #pragma unroll
        for (int db = 0; db < 4; ++db)
            #pragma unroll
            for (int r = 0; r < 4; ++r) {
                const int qrow = qr0 + quad * 4 + r;
                const int d = db * 16 + fr;
                ctx[((size_t)(b * SEQ + qrow)) * D_MODEL + hh * DP + d] =
                    (bf16)(o[db][r] / li[r]);
            }
    }
}

// ======================= launcher ==========================================
extern "C" void kernel_launch(void* const* d_in, const int* in_sizes, int n_in,
                              void* d_out, int out_size, void* d_ws, size_t ws_size,
                              hipStream_t stream) {
    const float* x       = (const float*)d_in[0];
    const float* wq_w    = (const float*)d_in[2];
    const float* wq_b    = (const float*)d_in[3];
    const float* wk_w    = (const float*)d_in[4];
    const float* wk_b    = (const float*)d_in[5];
    const float* wv_w    = (const float*)d_in[6];
    const float* wv_b    = (const float*)d_in[7];
    const float* dense_w = (const float*)d_in[8];
    const float* dense_b = (const float*)d_in[9];
    const float* gamma1  = (const float*)d_in[10];
    const float* beta1   = (const float*)d_in[11];
    const float* gamma2  = (const float*)d_in[12];
    const float* beta2   = (const float*)d_in[13];
    const float* fc_w    = (const float*)d_in[14];
    const float* proj_w  = (const float*)d_in[15];
    float* out = (float*)d_out;

    bf16* ws = (bf16*)d_ws;
    const size_t M1 = (size_t)1 << 20;
    bf16* xn   = ws;               // -> h -> hn in place
    bf16* qb   = ws + 4 * M1;
    bf16* kb   = ws + 8 * M1;
    bf16* vb   = ws + 12 * M1;
    bf16* ctx  = ws + 16 * M1;
    bf16* ff1  = qb;               // 16M elems overlay
    bf16* wqc  = ws + 20 * M1;
    bf16* wkc  = ws + 21 * M1;
    bf16* wvc  = ws + 22 * M1;
    bf16* wdc  = ws + 23 * M1;
    bf16* fcc  = ws + 24 * M1;
    bf16* prjc = ws + 28 * M1;
    bf16* h = xn, *hn = xn;

    // fused weight pre-conversion (fp32 -> bf16), one dispatch
    CvtArgs ca;
    ca.in[0] = (const float4*)wq_w;    ca.out[0] = (bf16x4*)wqc;
    ca.in[1] = (const float4*)wk_w;    ca.out[1] = (bf16x4*)wkc;
    ca.in[2] = (const float4*)wv_w;    ca.out[2] = (bf16x4*)wvc;
    ca.in[3] = (const float4*)dense_w; ca.out[3] = (bf16x4*)wdc;
    ca.in[4] = (const float4*)fc_w;    ca.out[4] = (bf16x4*)fcc;
    ca.in[5] = (const float4*)proj_w;  ca.out[5] = (bf16x4*)prjc;
    cvt_all<<<12288, 256, 0, stream>>>(ca);

    ln_kernel<float><<<TOK, 256, 0, stream>>>(x, gamma1, beta1, xn);
    gemm_qkv<<<dim3(24, 32), 256, 0, stream>>>(xn, wqc, wkc, wvc,
                                               wq_b, wk_b, wv_b, qb, kb, vb);
    attn_kernel<<<dim3(16, BB * NH), 256, 0, stream>>>(qb, kb, vb, ctx);
    gemm_bt64<1, bf16><<<dim3(16, 32), 256, 0, stream>>>(ctx, wdc, dense_b, xn, h,
                                                         TOK, D_MODEL, D_MODEL);
    ln_kernel<bf16><<<TOK, 256, 0, stream>>>(h, gamma2, beta2, hn);
    gemm_bt<2, bf16><<<dim3(32, 32), 256, 0, stream>>>(hn, fcc, nullptr, nullptr, ff1,
                                                       TOK, FFD, D_MODEL, 1.0f);
    gemm_bt64<3, float><<<dim3(16, 32), 256, 0, stream>>>(ff1, prjc, nullptr, hn, out,
                                                          TOK, D_MODEL, FFD);
}